// Round 1
// baseline (99.244 us; speedup 1.0000x reference)
//
#include <hip/hip_runtime.h>
#include <hip/hip_bf16.h>

// Bilinear CNN pooling: dotted[b,c,d] = sum_x L[b,x,c]*R[b,x,d]  (B=32, X=12544, C=128)
// then signed-sqrt + L2 normalize over the 16384-vector per batch.
//
// Strategy: K-split batched GEMM using split-bf16 3-pass MFMA (fp32-accurate,
// memory-bound), deterministic partials in device-global scratch, fused epilogue.

#define NK      16            // K-chunks per batch
#define KC      784           // 12544 / NK
#define KSTEPS  49            // KC / 16
#define BATCH   32
#define CDIM    128
#define XDIM    12544

typedef __bf16 bf16x8 __attribute__((ext_vector_type(8)));
typedef float  f32x16 __attribute__((ext_vector_type(16)));
typedef float  f32x4  __attribute__((ext_vector_type(4)));

// 32 MB partial buffer + per-segment sumsq. BSS device globals: fully rewritten
// every kernel_launch before being read, so no cross-call state dependence.
__device__ float g_part[(size_t)NK * BATCH * CDIM * CDIM];
__device__ float g_ssq[BATCH * 8];

// ---------------------------------------------------------------------------
// Kernel 1: per (chunk, batch) compute partial[c][d] = sum_{k in chunk} L[k][c]*R[k][d]
// 512 threads = 8 waves in a 2x4 grid of 64x32 output tiles (32x32x16 MFMA).
// LDS holds transposed hi/lo bf16 tiles: element(c,k) at
//   ((2c + (k>>3)) ^ ((c>>2)&7)) * 8 + (k&7)     (bf16 units)
// -> 16B-aligned contiguous reads for MFMA fragments, XOR kills the 128B-stride
//    bank pathology on the scattered b16 writes.
// ---------------------------------------------------------------------------
__global__ __launch_bounds__(512, 4)
void bcnn_gemm_kernel(const float* __restrict__ L, const float* __restrict__ R) {
  const int chunk = blockIdx.x;
  const int b     = blockIdx.y;
  const int t     = threadIdx.x;
  const int l     = t & 63;
  const int w     = t >> 6;
  const int wr    = w >> 2;      // 0..1  (64-row block)
  const int wc    = w & 3;       // 0..3  (32-col block)
  const int lc    = l & 31;
  const int h     = l >> 5;      // k-half selector for MFMA frags

  __shared__ __bf16 at_hi[2048];
  __shared__ __bf16 at_lo[2048];
  __shared__ __bf16 bt_hi[2048];
  __shared__ __bf16 bt_lo[2048];

  // staging assignment: thread loads float4 at (row = t>>5, c4 = (t&31)*4)
  const int trow = t >> 5;          // 0..15
  const int tc4  = (t & 31) << 2;   // 0..124
  const int fx   = t & 7;           // (c>>2)&7 for this thread's c-group
  const int hh   = trow >> 3;
  const int klow = trow & 7;

  int eoff[4];
#pragma unroll
  for (int j = 0; j < 4; ++j)
    eoff[j] = (((tc4 << 1) + (((j << 1) + hh) ^ fx)) << 3) + klow;

  const size_t gbase = ((size_t)b * XDIM + (size_t)chunk * KC + trow) * CDIM + tc4;
  const float* Lp = L + gbase;
  const float* Rp = R + gbase;

  // MFMA fragment read offsets (loop-invariant)
  const int cA0 = wr * 64 + lc;
  const int cA1 = cA0 + 32;
  const int dB  = wc * 32 + lc;
  const int offA0 = ((2 * cA0 + h) ^ ((cA0 >> 2) & 7)) << 3;
  const int offA1 = ((2 * cA1 + h) ^ ((cA1 >> 2) & 7)) << 3;
  const int offB  = ((2 * dB  + h) ^ ((dB  >> 2) & 7)) << 3;

  f32x16 acc0 = {};
  f32x16 acc1 = {};

  f32x4 lv = *(const f32x4*)Lp;
  f32x4 rv = *(const f32x4*)Rp;

  for (int s = 0; s < KSTEPS; ++s) {
    Lp += 16 * CDIM;
    Rp += 16 * CDIM;
    // prefetch next tile (dummy in-bounds address on the last step)
    const float* Lpn = (s < KSTEPS - 1) ? Lp : L;
    const float* Rpn = (s < KSTEPS - 1) ? Rp : R;
    f32x4 lvn = *(const f32x4*)Lpn;
    f32x4 rvn = *(const f32x4*)Rpn;

    __syncthreads();   // previous iteration's frag reads done
#pragma unroll
    for (int j = 0; j < 4; ++j) {
      float fl = lv[j];
      __bf16 lh = (__bf16)fl;
      __bf16 ll = (__bf16)(fl - (float)lh);
      at_hi[eoff[j]] = lh;
      at_lo[eoff[j]] = ll;
      float fr = rv[j];
      __bf16 rh = (__bf16)fr;
      __bf16 rl = (__bf16)(fr - (float)rh);
      bt_hi[eoff[j]] = rh;
      bt_lo[eoff[j]] = rl;
    }
    __syncthreads();

    bf16x8 ah0 = *(bf16x8*)&at_hi[offA0];
    bf16x8 al0 = *(bf16x8*)&at_lo[offA0];
    bf16x8 ah1 = *(bf16x8*)&at_hi[offA1];
    bf16x8 al1 = *(bf16x8*)&at_lo[offA1];
    bf16x8 bh  = *(bf16x8*)&bt_hi[offB];
    bf16x8 bl  = *(bf16x8*)&bt_lo[offB];

    // split-fp32: acc += ah*bh + ah*bl + al*bh   (al*bl ~2^-18, dropped)
    acc0 = __builtin_amdgcn_mfma_f32_32x32x16_bf16(ah0, bh, acc0, 0, 0, 0);
    acc1 = __builtin_amdgcn_mfma_f32_32x32x16_bf16(ah1, bh, acc1, 0, 0, 0);
    acc0 = __builtin_amdgcn_mfma_f32_32x32x16_bf16(ah0, bl, acc0, 0, 0, 0);
    acc1 = __builtin_amdgcn_mfma_f32_32x32x16_bf16(ah1, bl, acc1, 0, 0, 0);
    acc0 = __builtin_amdgcn_mfma_f32_32x32x16_bf16(al0, bh, acc0, 0, 0, 0);
    acc1 = __builtin_amdgcn_mfma_f32_32x32x16_bf16(al1, bh, acc1, 0, 0, 0);

    lv = lvn;
    rv = rvn;
  }

  // C/D layout (verified m74/m101): col = lane&31, row = (reg&3)+8*(reg>>2)+4*(lane>>5)
  float* outp = g_part + (((size_t)chunk * BATCH + b) << 14);
#pragma unroll
  for (int r = 0; r < 16; ++r) {
    const int row = (r & 3) + ((r >> 2) << 3) + (h << 2);
    outp[(size_t)(wr * 64 + row) * CDIM + (wc * 32 + lc)]      = acc0[r];
    outp[(size_t)(wr * 64 + 32 + row) * CDIM + (wc * 32 + lc)] = acc1[r];
  }
}

// ---------------------------------------------------------------------------
// Kernel 2a: sum NK partials, signed-sqrt, write sqrted to out, per-segment sumsq
// grid (8 segments, 32 batches) x 256 threads; 8 elems/thread.
// ---------------------------------------------------------------------------
__global__ void bcnn_sqrt_kernel(float* __restrict__ out) {
  const int b   = blockIdx.y;
  const int seg = blockIdx.x;
  const int t   = threadIdx.x;
  const int base = seg * 2048;

  float s[8];
  float ss = 0.f;
#pragma unroll
  for (int j = 0; j < 8; ++j) {
    const int idx = base + t + (j << 8);
    float v = 0.f;
#pragma unroll
    for (int ch = 0; ch < NK; ++ch)
      v += g_part[(((size_t)ch * BATCH + b) << 14) + idx];
    float a  = sqrtf(fabsf(v) + 1e-9f);
    float sg = (v > 0.f) ? 1.f : ((v < 0.f) ? -1.f : 0.f);
    float sv = sg * a;
    s[j] = sv;
    ss += sv * sv;
    out[((size_t)b << 14) + idx] = sv;
  }

  // deterministic block reduce (wave shuffle + LDS)
#pragma unroll
  for (int o = 32; o > 0; o >>= 1) ss += __shfl_down(ss, o, 64);
  __shared__ float red[4];
  const int lane = t & 63, wid = t >> 6;
  if (lane == 0) red[wid] = ss;
  __syncthreads();
  if (t == 0) g_ssq[b * 8 + seg] = red[0] + red[1] + red[2] + red[3];
}

// ---------------------------------------------------------------------------
// Kernel 2b: scale by rsqrt(max(sumsq, 1e-12))
// ---------------------------------------------------------------------------
__global__ void bcnn_scale_kernel(float* __restrict__ out) {
  const int b   = blockIdx.y;
  const int seg = blockIdx.x;
  const int t   = threadIdx.x;

  float tot = 0.f;
#pragma unroll
  for (int i = 0; i < 8; ++i) tot += g_ssq[b * 8 + i];
  const float scale = rsqrtf(fmaxf(tot, 1e-12f));

  const size_t base = ((size_t)b << 14) + seg * 2048 + t;
#pragma unroll
  for (int j = 0; j < 8; ++j) out[base + ((size_t)j << 8)] *= scale;
}

extern "C" void kernel_launch(void* const* d_in, const int* in_sizes, int n_in,
                              void* d_out, int out_size, void* d_ws, size_t ws_size,
                              hipStream_t stream) {
  const float* L = (const float*)d_in[0];
  const float* R = (const float*)d_in[1];
  float* out = (float*)d_out;

  dim3 g1(NK, BATCH);
  bcnn_gemm_kernel<<<g1, 512, 0, stream>>>(L, R);

  dim3 g2(8, BATCH);
  bcnn_sqrt_kernel<<<g2, 256, 0, stream>>>(out);
  bcnn_scale_kernel<<<g2, 256, 0, stream>>>(out);
}